// Round 8
// baseline (1067.025 us; speedup 1.0000x reference)
//
#include <hip/hip_runtime.h>

#define NNODES 20000
#define EEDGES 320000
#define DD     256
#define NEG_SLOPE 0.2f
#define SCAN_BLOCKS ((NNODES + 255) / 256)

// ---------------- CSR build ----------------

__global__ void zero_ints_k(int* __restrict__ p, int n) {
    int i = blockIdx.x * 256 + threadIdx.x;
    if (i < n) p[i] = 0;
}

__global__ void hist_k(const int* __restrict__ dst, int* __restrict__ rowptr) {
    int i = blockIdx.x * 256 + threadIdx.x;
    if (i < EEDGES) atomicAdd(&rowptr[dst[i] + 1], 1);
}

__global__ __launch_bounds__(256) void scan1_k(int* __restrict__ rowptr, int* __restrict__ bsums) {
    __shared__ int buf[256];
    int idx = blockIdx.x * 256 + threadIdx.x;
    int v = (idx < NNODES) ? rowptr[idx + 1] : 0;
    buf[threadIdx.x] = v;
    __syncthreads();
#pragma unroll
    for (int off = 1; off < 256; off <<= 1) {
        int t = (threadIdx.x >= (unsigned)off) ? buf[threadIdx.x - off] : 0;
        __syncthreads();
        buf[threadIdx.x] += t;
        __syncthreads();
    }
    if (idx < NNODES) rowptr[idx + 1] = buf[threadIdx.x];
    if (threadIdx.x == 255) bsums[blockIdx.x] = buf[255];
}

__global__ __launch_bounds__(128) void scan2_k(int* __restrict__ bsums) {
    __shared__ int buf[128];
    int v = (threadIdx.x < SCAN_BLOCKS) ? bsums[threadIdx.x] : 0;
    buf[threadIdx.x] = v;
    __syncthreads();
#pragma unroll
    for (int off = 1; off < 128; off <<= 1) {
        int t = (threadIdx.x >= (unsigned)off) ? buf[threadIdx.x - off] : 0;
        __syncthreads();
        buf[threadIdx.x] += t;
        __syncthreads();
    }
    if (threadIdx.x < SCAN_BLOCKS) bsums[threadIdx.x] = buf[threadIdx.x];
}

// adds block offsets AND writes the scatter cursor (merged copy_cursor)
__global__ void scan3_k(int* __restrict__ rowptr, const int* __restrict__ bsums,
                        int* __restrict__ cursor) {
    int idx = blockIdx.x * 256 + threadIdx.x;
    if (idx < NNODES) {
        int v = rowptr[idx + 1];
        if (blockIdx.x > 0) { v += bsums[blockIdx.x - 1]; rowptr[idx + 1] = v; }
        if (idx + 1 < NNODES) cursor[idx + 1] = v;
        if (idx == 0) cursor[0] = 0;
    }
}

__global__ void scatter_k(const int* __restrict__ src, const int* __restrict__ dst,
                          int* __restrict__ cursor, int* __restrict__ colsrc) {
    int i = blockIdx.x * 256 + threadIdx.x;
    if (i < EEDGES) {
        int d = dst[i];
        int pos = atomicAdd(&cursor[d], 1);
        colsrc[pos] = src[i];
    }
}

// ---------------- W3 folding: concat(h,h)@W3 == relu(h)@(W3_top+W3_bot) ----------------

__global__ void w3sum_k(const float* __restrict__ W3, float* __restrict__ wsum) {
    int i = blockIdx.x * 256 + threadIdx.x;
    if (i < DD * DD) wsum[i] = W3[i] + W3[i + DD * DD];
}

// ---------------- fp32 GEMM: C[M,256] = act(A)[M,256] @ B[256,256] ----------------
// 64x64 tile, 128 threads, 8x4 micro (R4-proven), BK=32: 8 K-slabs, 16 barriers
// total (vs 32 at BK=16), 1024 FMA-instructions of prefetch cover per slab.

template<bool RELU_A>
__global__ __launch_bounds__(128, 4) void gemm_k(const float* __restrict__ A,
                                                 const float* __restrict__ B,
                                                 float* __restrict__ C, int M) {
    __shared__ float As[32][68];   // transposed, padded: writes 2-way max (free)
    __shared__ float Bs[32][64];
    const int t  = threadIdx.x;
    const int tx = t & 15;   // col group (4 cols)
    const int ty = t >> 4;   // row group (8 rows)
    const int rowBase = blockIdx.y * 64;
    const int colBase = blockIdx.x * 64;

    float acc[8][4];
#pragma unroll
    for (int i = 0; i < 8; ++i)
#pragma unroll
        for (int j = 0; j < 4; ++j) acc[i][j] = 0.f;

    const int ar = t >> 1;          // 0..63  A row in tile
    const int ac = (t & 1) * 16;    // 0 or 16 A k-offset
    const int br = t >> 4;          // 0..7   B k-row
    const int bc = (t & 15) * 4;    // 0..60  B col
    const int arow = rowBase + ar;

    float4 a0 = make_float4(0.f, 0.f, 0.f, 0.f), a1 = a0, a2 = a0, a3 = a0;
    float4 b0, b1, b2, b3;
    if (arow < M) {
        const float* ap = A + (size_t)arow * DD + ac;
        a0 = *(const float4*)(ap + 0);
        a1 = *(const float4*)(ap + 4);
        a2 = *(const float4*)(ap + 8);
        a3 = *(const float4*)(ap + 12);
    }
    {
        const float* bp = B + colBase + bc;
        b0 = *(const float4*)(bp + (size_t)(br     ) * DD);
        b1 = *(const float4*)(bp + (size_t)(br +  8) * DD);
        b2 = *(const float4*)(bp + (size_t)(br + 16) * DD);
        b3 = *(const float4*)(bp + (size_t)(br + 24) * DD);
    }

    for (int s = 0; s < 8; ++s) {
        if (RELU_A) {
            a0.x = fmaxf(a0.x, 0.f); a0.y = fmaxf(a0.y, 0.f);
            a0.z = fmaxf(a0.z, 0.f); a0.w = fmaxf(a0.w, 0.f);
            a1.x = fmaxf(a1.x, 0.f); a1.y = fmaxf(a1.y, 0.f);
            a1.z = fmaxf(a1.z, 0.f); a1.w = fmaxf(a1.w, 0.f);
            a2.x = fmaxf(a2.x, 0.f); a2.y = fmaxf(a2.y, 0.f);
            a2.z = fmaxf(a2.z, 0.f); a2.w = fmaxf(a2.w, 0.f);
            a3.x = fmaxf(a3.x, 0.f); a3.y = fmaxf(a3.y, 0.f);
            a3.z = fmaxf(a3.z, 0.f); a3.w = fmaxf(a3.w, 0.f);
        }
        __syncthreads();
        As[ac +  0][ar] = a0.x; As[ac +  1][ar] = a0.y;
        As[ac +  2][ar] = a0.z; As[ac +  3][ar] = a0.w;
        As[ac +  4][ar] = a1.x; As[ac +  5][ar] = a1.y;
        As[ac +  6][ar] = a1.z; As[ac +  7][ar] = a1.w;
        As[ac +  8][ar] = a2.x; As[ac +  9][ar] = a2.y;
        As[ac + 10][ar] = a2.z; As[ac + 11][ar] = a2.w;
        As[ac + 12][ar] = a3.x; As[ac + 13][ar] = a3.y;
        As[ac + 14][ar] = a3.z; As[ac + 15][ar] = a3.w;
        *(float4*)&Bs[br     ][bc] = b0;
        *(float4*)&Bs[br +  8][bc] = b1;
        *(float4*)&Bs[br + 16][bc] = b2;
        *(float4*)&Bs[br + 24][bc] = b3;
        __syncthreads();

        if (s < 7) {
            int kn = (s + 1) * 32;
            if (arow < M) {
                const float* ap = A + (size_t)arow * DD + kn + ac;
                a0 = *(const float4*)(ap + 0);
                a1 = *(const float4*)(ap + 4);
                a2 = *(const float4*)(ap + 8);
                a3 = *(const float4*)(ap + 12);
            }
            const float* bp = B + (size_t)kn * DD + colBase + bc;
            b0 = *(const float4*)(bp + (size_t)(br     ) * DD);
            b1 = *(const float4*)(bp + (size_t)(br +  8) * DD);
            b2 = *(const float4*)(bp + (size_t)(br + 16) * DD);
            b3 = *(const float4*)(bp + (size_t)(br + 24) * DD);
        }

#pragma unroll
        for (int kk = 0; kk < 32; ++kk) {
            float a[8], b[4];
            *(float4*)&a[0] = *(const float4*)&As[kk][ty * 8];
            *(float4*)&a[4] = *(const float4*)&As[kk][ty * 8 + 4];
            *(float4*)&b[0] = *(const float4*)&Bs[kk][tx * 4];
#pragma unroll
            for (int i = 0; i < 8; ++i)
#pragma unroll
                for (int j = 0; j < 4; ++j)
                    acc[i][j] = fmaf(a[i], b[j], acc[i][j]);
        }
    }

#pragma unroll
    for (int i = 0; i < 8; ++i) {
        int r = rowBase + ty * 8 + i;
        if (r < M) {
            float4 o = make_float4(acc[i][0], acc[i][1], acc[i][2], acc[i][3]);
            *(float4*)(C + (size_t)r * DD + colBase + tx * 4) = o;
        }
    }
}

// ---------------- per-node attention dots ----------------

__global__ __launch_bounds__(256) void dots_k(const float* __restrict__ hw,
                                              const float* __restrict__ asrc,
                                              const float* __restrict__ adst,
                                              float* __restrict__ es, float* __restrict__ ed) {
    int wave = threadIdx.x >> 6;
    int lane = threadIdx.x & 63;
    int node = blockIdx.x * 4 + wave;
    if (node >= NNODES) return;
    float4 v = *(const float4*)(hw + (size_t)node * DD + lane * 4);
    float4 a = *(const float4*)(asrc + lane * 4);
    float4 b = *(const float4*)(adst + lane * 4);
    float s = v.x * a.x + v.y * a.y + v.z * a.z + v.w * a.w;
    float d = v.x * b.x + v.y * b.y + v.z * b.z + v.w * b.w;
#pragma unroll
    for (int off = 32; off; off >>= 1) {
        s += __shfl_xor(s, off);
        d += __shfl_xor(d, off);
    }
    if (lane == 0) { es[node] = s; ed[node] = d; }
}

// ---------------- fused segment softmax + weighted aggregation ----------------
// one wave per node; deg<=64 path keeps scores in registers (alpha via shuffle);
// gather 8-wide into NAMED accumulators (compile-time register indices only —
// dynamic indexing demotes arrays to scratch: round-5 lesson).

__global__ __launch_bounds__(256) void gat_agg_k(const float* __restrict__ hw,
                                                 const float* __restrict__ es,
                                                 const float* __restrict__ ed,
                                                 const int* __restrict__ rowptr,
                                                 const int* __restrict__ colsrc,
                                                 float* __restrict__ ealpha,
                                                 const float* __restrict__ bias,
                                                 float* __restrict__ hout) {
    int wave = threadIdx.x >> 6;
    int lane = threadIdx.x & 63;
    int node = blockIdx.x * 4 + wave;
    if (node >= NNODES) return;
    int start = rowptr[node], end = rowptr[node + 1];
    int deg = end - start;
    float edd = ed[node];

    float4 acc0 = make_float4(0.f, 0.f, 0.f, 0.f);
    float4 acc1 = acc0, acc2 = acc0, acc3 = acc0;
    float4 acc4 = acc0, acc5 = acc0, acc6 = acc0, acc7 = acc0;

#define FMA4(ACC, W, V) \
    ACC.x = fmaf(W, V.x, ACC.x); ACC.y = fmaf(W, V.y, ACC.y); \
    ACC.z = fmaf(W, V.z, ACC.z); ACC.w = fmaf(W, V.w, ACC.w);

    if (deg <= 64) {
        if (deg > 0) {
            int j = start + lane;
            bool valid = j < end;
            int msrc = valid ? colsrc[j] : 0;
            float e = valid ? es[msrc] + edd : -INFINITY;
            e = fmaxf(e, NEG_SLOPE * e);                  // leaky_relu
            float mx = e;
#pragma unroll
            for (int off = 32; off; off >>= 1) mx = fmaxf(mx, __shfl_xor(mx, off));
            float ee = valid ? expf(e - mx) : 0.f;
            float sum = ee;
#pragma unroll
            for (int off = 32; off; off >>= 1) sum += __shfl_xor(sum, off);
            float w = ee / sum;                            // this lane's alpha

            int j2 = 0;
            for (; j2 + 8 <= deg; j2 += 8) {
                int s0 = __shfl(msrc, j2 + 0), s1 = __shfl(msrc, j2 + 1);
                int s2 = __shfl(msrc, j2 + 2), s3 = __shfl(msrc, j2 + 3);
                int s4 = __shfl(msrc, j2 + 4), s5 = __shfl(msrc, j2 + 5);
                int s6 = __shfl(msrc, j2 + 6), s7 = __shfl(msrc, j2 + 7);
                float w0 = __shfl(w, j2 + 0), w1 = __shfl(w, j2 + 1);
                float w2 = __shfl(w, j2 + 2), w3 = __shfl(w, j2 + 3);
                float w4 = __shfl(w, j2 + 4), w5 = __shfl(w, j2 + 5);
                float w6 = __shfl(w, j2 + 6), w7 = __shfl(w, j2 + 7);
                float4 v0 = *(const float4*)(hw + (size_t)s0 * DD + lane * 4);
                float4 v1 = *(const float4*)(hw + (size_t)s1 * DD + lane * 4);
                float4 v2 = *(const float4*)(hw + (size_t)s2 * DD + lane * 4);
                float4 v3 = *(const float4*)(hw + (size_t)s3 * DD + lane * 4);
                float4 v4 = *(const float4*)(hw + (size_t)s4 * DD + lane * 4);
                float4 v5 = *(const float4*)(hw + (size_t)s5 * DD + lane * 4);
                float4 v6 = *(const float4*)(hw + (size_t)s6 * DD + lane * 4);
                float4 v7 = *(const float4*)(hw + (size_t)s7 * DD + lane * 4);
                FMA4(acc0, w0, v0); FMA4(acc1, w1, v1);
                FMA4(acc2, w2, v2); FMA4(acc3, w3, v3);
                FMA4(acc4, w4, v4); FMA4(acc5, w5, v5);
                FMA4(acc6, w6, v6); FMA4(acc7, w7, v7);
            }
            if (j2 + 4 <= deg) {
                int s0 = __shfl(msrc, j2 + 0), s1 = __shfl(msrc, j2 + 1);
                int s2 = __shfl(msrc, j2 + 2), s3 = __shfl(msrc, j2 + 3);
                float w0 = __shfl(w, j2 + 0), w1 = __shfl(w, j2 + 1);
                float w2 = __shfl(w, j2 + 2), w3 = __shfl(w, j2 + 3);
                float4 v0 = *(const float4*)(hw + (size_t)s0 * DD + lane * 4);
                float4 v1 = *(const float4*)(hw + (size_t)s1 * DD + lane * 4);
                float4 v2 = *(const float4*)(hw + (size_t)s2 * DD + lane * 4);
                float4 v3 = *(const float4*)(hw + (size_t)s3 * DD + lane * 4);
                FMA4(acc0, w0, v0); FMA4(acc1, w1, v1);
                FMA4(acc2, w2, v2); FMA4(acc3, w3, v3);
                j2 += 4;
            }
            for (; j2 < deg; ++j2) {
                int   s0 = __shfl(msrc, j2);
                float w0 = __shfl(w, j2);
                float4 v0 = *(const float4*)(hw + (size_t)s0 * DD + lane * 4);
                FMA4(acc0, w0, v0);
            }
        }
    } else {
        // rare fallback: deg > 64, global scratch
        float mx = -INFINITY;
        for (int j = start + lane; j < end; j += 64) {
            float e = es[colsrc[j]] + edd;
            e = fmaxf(e, NEG_SLOPE * e);
            mx = fmaxf(mx, e);
        }
#pragma unroll
        for (int off = 32; off; off >>= 1) mx = fmaxf(mx, __shfl_xor(mx, off));
        float sum = 0.f;
        for (int j = start + lane; j < end; j += 64) {
            float e = es[colsrc[j]] + edd;
            e = fmaxf(e, NEG_SLOPE * e);
            float ee = expf(e - mx);
            ealpha[j] = ee;
            sum += ee;
        }
#pragma unroll
        for (int off = 32; off; off >>= 1) sum += __shfl_xor(sum, off);
        float inv = 1.f / sum;
        int j = start;
        for (; j + 4 <= end; j += 4) {
            int s0 = colsrc[j], s1 = colsrc[j + 1], s2 = colsrc[j + 2], s3 = colsrc[j + 3];
            float w0 = ealpha[j] * inv, w1 = ealpha[j + 1] * inv;
            float w2 = ealpha[j + 2] * inv, w3 = ealpha[j + 3] * inv;
            float4 v0 = *(const float4*)(hw + (size_t)s0 * DD + lane * 4);
            float4 v1 = *(const float4*)(hw + (size_t)s1 * DD + lane * 4);
            float4 v2 = *(const float4*)(hw + (size_t)s2 * DD + lane * 4);
            float4 v3 = *(const float4*)(hw + (size_t)s3 * DD + lane * 4);
            FMA4(acc0, w0, v0); FMA4(acc1, w1, v1);
            FMA4(acc2, w2, v2); FMA4(acc3, w3, v3);
        }
        for (; j < end; ++j) {
            int s0 = colsrc[j];
            float w0 = ealpha[j] * inv;
            float4 v0 = *(const float4*)(hw + (size_t)s0 * DD + lane * 4);
            FMA4(acc0, w0, v0);
        }
    }
#undef FMA4

    acc0.x += acc4.x; acc0.y += acc4.y; acc0.z += acc4.z; acc0.w += acc4.w;
    acc1.x += acc5.x; acc1.y += acc5.y; acc1.z += acc5.z; acc1.w += acc5.w;
    acc2.x += acc6.x; acc2.y += acc6.y; acc2.z += acc6.z; acc2.w += acc6.w;
    acc3.x += acc7.x; acc3.y += acc7.y; acc3.z += acc7.z; acc3.w += acc7.w;
    acc0.x += acc1.x; acc0.y += acc1.y; acc0.z += acc1.z; acc0.w += acc1.w;
    acc2.x += acc3.x; acc2.y += acc3.y; acc2.z += acc3.z; acc2.w += acc3.w;
    acc0.x += acc2.x; acc0.y += acc2.y; acc0.z += acc2.z; acc0.w += acc2.w;
    float4 b4 = *(const float4*)(bias + lane * 4);
    acc0.x += b4.x; acc0.y += b4.y; acc0.z += b4.z; acc0.w += b4.w;
    *(float4*)(hout + (size_t)node * DD + lane * 4) = acc0;
}

// ---------------- driver ----------------

extern "C" void kernel_launch(void* const* d_in, const int* in_sizes, int n_in,
                              void* d_out, int out_size, void* d_ws, size_t ws_size,
                              hipStream_t stream) {
    const float* x     = (const float*)d_in[0];
    const int*   ei    = (const int*)d_in[1];     // [2,E]: first E = src, next E = dst
    const float* W1    = (const float*)d_in[2];
    const float* W2    = (const float*)d_in[3];
    const float* Ws    = (const float*)d_in[4];   // [6,256,256]
    const float* a_src = (const float*)d_in[5];   // [6,256]
    const float* a_dst = (const float*)d_in[6];
    const float* bias  = (const float*)d_in[7];   // [6,256]
    const float* W3    = (const float*)d_in[8];   // [512,256]
    float* out = (float*)d_out;

    const int* src = ei;
    const int* dst = ei + EEDGES;

    // workspace carve-up
    float* bufA   = (float*)d_ws;                      // N*D
    float* bufB   = bufA + (size_t)NNODES * DD;        // N*D
    float* es     = bufB + (size_t)NNODES * DD;        // N
    float* edv    = es + NNODES;                       // N
    float* ealpha = edv + NNODES;                      // E
    float* w3s    = ealpha + EEDGES;                   // 256*256
    int*   rowptr = (int*)(w3s + DD * DD);             // N+1
    int*   cursor = rowptr + (NNODES + 1);             // N
    int*   colsrc = cursor + NNODES;                   // E
    int*   bsums  = colsrc + EEDGES;                   // SCAN_BLOCKS

    // --- CSR build (per call; harness poisons ws) ---
    zero_ints_k<<<(NNODES + 1 + 255) / 256, 256, 0, stream>>>(rowptr, NNODES + 1);
    hist_k<<<(EEDGES + 255) / 256, 256, 0, stream>>>(dst, rowptr);
    scan1_k<<<SCAN_BLOCKS, 256, 0, stream>>>(rowptr, bsums);
    scan2_k<<<1, 128, 0, stream>>>(bsums);
    scan3_k<<<SCAN_BLOCKS, 256, 0, stream>>>(rowptr, bsums, cursor);
    scatter_k<<<(EEDGES + 255) / 256, 256, 0, stream>>>(src, dst, cursor, colsrc);
    w3sum_k<<<(DD * DD + 255) / 256, 256, 0, stream>>>(W3, w3s);

    dim3 ggrid(DD / 64, (NNODES + 63) / 64);
    const int nodeBlocks = (NNODES + 3) / 4;

    // h = (x @ W1) @ W2
    gemm_k<false><<<ggrid, 128, 0, stream>>>(x, W1, bufA, NNODES);
    gemm_k<false><<<ggrid, 128, 0, stream>>>(bufA, W2, bufB, NNODES);

    // 6 GAT layers; cur lives in bufB, hw in bufA each layer
    for (int l = 0; l < 6; ++l) {
        gemm_k<false><<<ggrid, 128, 0, stream>>>(bufB, Ws + (size_t)l * DD * DD, bufA, NNODES);
        dots_k<<<nodeBlocks, 256, 0, stream>>>(bufA, a_src + (size_t)l * DD, a_dst + (size_t)l * DD, es, edv);
        gat_agg_k<<<nodeBlocks, 256, 0, stream>>>(bufA, es, edv, rowptr, colsrc, ealpha,
                                                  bias + (size_t)l * DD, bufB);
    }

    // out = relu(h) @ (W3_top + W3_bot)
    gemm_k<true><<<ggrid, 128, 0, stream>>>(bufB, w3s, out, NNODES);
}

// Round 9
// 648.891 us; speedup vs baseline: 1.6444x; 1.6444x over previous
//
#include <hip/hip_runtime.h>
#include <hip/hip_fp16.h>
#include <stdint.h>

#define NNODES 20000
#define EEDGES 320000
#define DD     256
#define NEG_SLOPE 0.2f
#define SCAN_BLOCKS ((NNODES + 255) / 256)

typedef _Float16 half8 __attribute__((ext_vector_type(8)));
typedef _Float16 half4 __attribute__((ext_vector_type(4)));
typedef float f32x4 __attribute__((ext_vector_type(4)));

// ---------------- CSR build ----------------

__global__ void zero_ints_k(int* __restrict__ p, int n) {
    int i = blockIdx.x * 256 + threadIdx.x;
    if (i < n) p[i] = 0;
}

__global__ void hist_k(const int* __restrict__ dst, int* __restrict__ rowptr) {
    int i = blockIdx.x * 256 + threadIdx.x;
    if (i < EEDGES) atomicAdd(&rowptr[dst[i] + 1], 1);
}

__global__ __launch_bounds__(256) void scan1_k(int* __restrict__ rowptr, int* __restrict__ bsums) {
    __shared__ int buf[256];
    int idx = blockIdx.x * 256 + threadIdx.x;
    int v = (idx < NNODES) ? rowptr[idx + 1] : 0;
    buf[threadIdx.x] = v;
    __syncthreads();
#pragma unroll
    for (int off = 1; off < 256; off <<= 1) {
        int t = (threadIdx.x >= (unsigned)off) ? buf[threadIdx.x - off] : 0;
        __syncthreads();
        buf[threadIdx.x] += t;
        __syncthreads();
    }
    if (idx < NNODES) rowptr[idx + 1] = buf[threadIdx.x];
    if (threadIdx.x == 255) bsums[blockIdx.x] = buf[255];
}

__global__ __launch_bounds__(128) void scan2_k(int* __restrict__ bsums) {
    __shared__ int buf[128];
    int v = (threadIdx.x < SCAN_BLOCKS) ? bsums[threadIdx.x] : 0;
    buf[threadIdx.x] = v;
    __syncthreads();
#pragma unroll
    for (int off = 1; off < 128; off <<= 1) {
        int t = (threadIdx.x >= (unsigned)off) ? buf[threadIdx.x - off] : 0;
        __syncthreads();
        buf[threadIdx.x] += t;
        __syncthreads();
    }
    if (threadIdx.x < SCAN_BLOCKS) bsums[threadIdx.x] = buf[threadIdx.x];
}

// adds block offsets AND writes the scatter cursor
__global__ void scan3_k(int* __restrict__ rowptr, const int* __restrict__ bsums,
                        int* __restrict__ cursor) {
    int idx = blockIdx.x * 256 + threadIdx.x;
    if (idx < NNODES) {
        int v = rowptr[idx + 1];
        if (blockIdx.x > 0) { v += bsums[blockIdx.x - 1]; rowptr[idx + 1] = v; }
        if (idx + 1 < NNODES) cursor[idx + 1] = v;
        if (idx == 0) cursor[0] = 0;
    }
}

__global__ void scatter_k(const int* __restrict__ src, const int* __restrict__ dst,
                          int* __restrict__ cursor, int* __restrict__ colsrc) {
    int i = blockIdx.x * 256 + threadIdx.x;
    if (i < EEDGES) {
        int d = dst[i];
        int pos = atomicAdd(&cursor[d], 1);
        colsrc[pos] = src[i];
    }
}

// ---------------- fp32 -> fp16 hi/lo split (row-major, for A side) ----------------

__global__ void cvt_split_k(const float* __restrict__ X, _Float16* __restrict__ Xh,
                            _Float16* __restrict__ Xl, int n) {
    int i = blockIdx.x * 256 + threadIdx.x;
    if (i < n) {
        float v = X[i];
        _Float16 hi = (_Float16)v;
        Xh[i] = hi;
        Xl[i] = (_Float16)(v - (float)hi);
    }
}

// ---------------- weight: W[K][N] fp32 -> W^T hi/lo [N][K] fp16 (optional W3 fold) ----

template<bool SUM>
__global__ void cvt_w_k(const float* __restrict__ W, _Float16* __restrict__ Wh,
                        _Float16* __restrict__ Wl) {
    int i = blockIdx.x * 256 + threadIdx.x;   // over 65536
    if (i < DD * DD) {
        int k = i >> 8, n = i & 255;
        float v = W[i];
        if (SUM) v += W[i + DD * DD];
        _Float16 hi = (_Float16)v;
        Wh[n * DD + k] = hi;
        Wl[n * DD + k] = (_Float16)(v - (float)hi);
    }
}

// ---------------- split-fp16 MFMA GEMM: C[M,256] = (Ahi+Alo) @ (Bhi+Blo) ----------------
// A: row-major [M][256] fp16 pairs. B: transposed [N=256][K=256] fp16 pairs.
// Block 64x64 (4 waves, wave=32x32 = 2x2 mfma_f32_16x16x32_f16 tiles, 4 products each).
// Fragment layouts (verified, learn_hip m89/m91/m120): A/B operand [idx=lane&15][k=(lane>>4)*8+j],
// C/D col=lane&15, row=(lane>>4)*4+reg. LDS pitch 40 halves -> <=2-way banks (free).

template<bool OUT_SPLIT>
__global__ __launch_bounds__(256) void gemm16_k(
    const _Float16* __restrict__ Ah, const _Float16* __restrict__ Al,
    const _Float16* __restrict__ Bh, const _Float16* __restrict__ Bl,
    float* __restrict__ C, _Float16* __restrict__ Ch, _Float16* __restrict__ Cl, int M)
{
    __shared__ _Float16 As_h[64][40], As_l[64][40], Bs_h[64][40], Bs_l[64][40];
    const int t = threadIdx.x;
    const int lane = t & 63;
    const int w = t >> 6;
    const int rowBase = blockIdx.y * 64;
    const int colBase = blockIdx.x * 64;
    const int mo = (w & 1) * 32;
    const int no = (w >> 1) * 32;

    const int srow = t >> 2;          // 0..63
    const int sseg = (t & 3) * 8;     // 0,8,16,24 halves
    const int garow = rowBase + srow;
    const size_t aoff = (size_t)garow * DD + sseg;
    const size_t boff = (size_t)(colBase + srow) * DD + sseg;

    f32x4 acc00 = {0.f,0.f,0.f,0.f}, acc01 = acc00, acc10 = acc00, acc11 = acc00;
    const int4 zero4 = make_int4(0, 0, 0, 0);
    int4 ra_h, ra_l, rb_h, rb_l;

    ra_h = (garow < M) ? *(const int4*)(Ah + aoff) : zero4;
    ra_l = (garow < M) ? *(const int4*)(Al + aoff) : zero4;
    rb_h = *(const int4*)(Bh + boff);
    rb_l = *(const int4*)(Bl + boff);

    for (int s = 0; s < 8; ++s) {
        __syncthreads();
        *(int4*)&As_h[srow][sseg] = ra_h;
        *(int4*)&As_l[srow][sseg] = ra_l;
        *(int4*)&Bs_h[srow][sseg] = rb_h;
        *(int4*)&Bs_l[srow][sseg] = rb_l;
        __syncthreads();

        if (s < 7) {
            int kn = (s + 1) * 32;
            ra_h = (garow < M) ? *(const int4*)(Ah + aoff + kn) : zero4;
            ra_l = (garow < M) ? *(const int4*)(Al + aoff + kn) : zero4;
            rb_h = *(const int4*)(Bh + boff + kn);
            rb_l = *(const int4*)(Bl + boff + kn);
        }

        const int fr = lane & 15;
        const int fq = (lane >> 4) * 8;
        half8 a0h = *(const half8*)&As_h[mo + fr     ][fq];
        half8 a1h = *(const half8*)&As_h[mo + 16 + fr][fq];
        half8 a0l = *(const half8*)&As_l[mo + fr     ][fq];
        half8 a1l = *(const half8*)&As_l[mo + 16 + fr][fq];
        half8 b0h = *(const half8*)&Bs_h[no + fr     ][fq];
        half8 b1h = *(const half8*)&Bs_h[no + 16 + fr][fq];
        half8 b0l = *(const half8*)&Bs_l[no + fr     ][fq];
        half8 b1l = *(const half8*)&Bs_l[no + 16 + fr][fq];

        acc00 = __builtin_amdgcn_mfma_f32_16x16x32_f16(a0h, b0h, acc00, 0, 0, 0);
        acc01 = __builtin_amdgcn_mfma_f32_16x16x32_f16(a0h, b1h, acc01, 0, 0, 0);
        acc10 = __builtin_amdgcn_mfma_f32_16x16x32_f16(a1h, b0h, acc10, 0, 0, 0);
        acc11 = __builtin_amdgcn_mfma_f32_16x16x32_f16(a1h, b1h, acc11, 0, 0, 0);
        acc00 = __builtin_amdgcn_mfma_f32_16x16x32_f16(a0h, b0l, acc00, 0, 0, 0);
        acc01 = __builtin_amdgcn_mfma_f32_16x16x32_f16(a0h, b1l, acc01, 0, 0, 0);
        acc10 = __builtin_amdgcn_mfma_f32_16x16x32_f16(a1h, b0l, acc10, 0, 0, 0);
        acc11 = __builtin_amdgcn_mfma_f32_16x16x32_f16(a1h, b1l, acc11, 0, 0, 0);
        acc00 = __builtin_amdgcn_mfma_f32_16x16x32_f16(a0l, b0h, acc00, 0, 0, 0);
        acc01 = __builtin_amdgcn_mfma_f32_16x16x32_f16(a0l, b1h, acc01, 0, 0, 0);
        acc10 = __builtin_amdgcn_mfma_f32_16x16x32_f16(a1l, b0h, acc10, 0, 0, 0);
        acc11 = __builtin_amdgcn_mfma_f32_16x16x32_f16(a1l, b1h, acc11, 0, 0, 0);
        acc00 = __builtin_amdgcn_mfma_f32_16x16x32_f16(a0l, b0l, acc00, 0, 0, 0);
        acc01 = __builtin_amdgcn_mfma_f32_16x16x32_f16(a0l, b1l, acc01, 0, 0, 0);
        acc10 = __builtin_amdgcn_mfma_f32_16x16x32_f16(a1l, b0l, acc10, 0, 0, 0);
        acc11 = __builtin_amdgcn_mfma_f32_16x16x32_f16(a1l, b1l, acc11, 0, 0, 0);
    }

    const int ccol = lane & 15;
    const int crq = (lane >> 4) * 4;
#define EPI(ACC, MI, NI) \
    _Pragma("unroll") \
    for (int r = 0; r < 4; ++r) { \
        int grow = rowBase + mo + 16 * MI + crq + r; \
        if (grow < M) { \
            int gcol = colBase + no + 16 * NI + ccol; \
            float v = ACC[r]; \
            if (OUT_SPLIT) { \
                _Float16 hi = (_Float16)v; \
                Ch[(size_t)grow * DD + gcol] = hi; \
                Cl[(size_t)grow * DD + gcol] = (_Float16)(v - (float)hi); \
            } else { \
                C[(size_t)grow * DD + gcol] = v; \
            } \
        } \
    }
    EPI(acc00, 0, 0) EPI(acc01, 0, 1) EPI(acc10, 1, 0) EPI(acc11, 1, 1)
#undef EPI
}

// ---------------- per-node attention dots (reads fp32 hw) ----------------

__global__ __launch_bounds__(256) void dots_k(const float* __restrict__ hw,
                                              const float* __restrict__ asrc,
                                              const float* __restrict__ adst,
                                              float* __restrict__ es, float* __restrict__ ed) {
    int wave = threadIdx.x >> 6;
    int lane = threadIdx.x & 63;
    int node = blockIdx.x * 4 + wave;
    if (node >= NNODES) return;
    float4 v = *(const float4*)(hw + (size_t)node * DD + lane * 4);
    float4 a = *(const float4*)(asrc + lane * 4);
    float4 b = *(const float4*)(adst + lane * 4);
    float s = v.x * a.x + v.y * a.y + v.z * a.z + v.w * a.w;
    float d = v.x * b.x + v.y * b.y + v.z * b.z + v.w * b.w;
#pragma unroll
    for (int off = 32; off; off >>= 1) {
        s += __shfl_xor(s, off);
        d += __shfl_xor(d, off);
    }
    if (lane == 0) { es[node] = s; ed[node] = d; }
}

// ---------------- fused segment softmax + aggregation; writes fp16 hi/lo split ----
// (R4-proven gather structure; epilogue adds bias, optional final relu, splits.)

template<bool RELU>
__global__ __launch_bounds__(256) void gat_agg_k(const float* __restrict__ hw,
                                                 const float* __restrict__ es,
                                                 const float* __restrict__ ed,
                                                 const int* __restrict__ rowptr,
                                                 const int* __restrict__ colsrc,
                                                 float* __restrict__ ealpha,
                                                 const float* __restrict__ bias,
                                                 _Float16* __restrict__ hh,
                                                 _Float16* __restrict__ hl) {
    int wave = threadIdx.x >> 6;
    int lane = threadIdx.x & 63;
    int node = blockIdx.x * 4 + wave;
    if (node >= NNODES) return;
    int start = rowptr[node], end = rowptr[node + 1];
    int deg = end - start;
    float edd = ed[node];

    float4 acc0 = make_float4(0.f, 0.f, 0.f, 0.f);
    float4 acc1 = acc0, acc2 = acc0, acc3 = acc0;
    float4 acc4 = acc0, acc5 = acc0, acc6 = acc0, acc7 = acc0;

#define FMA4(ACC, W, V) \
    ACC.x = fmaf(W, V.x, ACC.x); ACC.y = fmaf(W, V.y, ACC.y); \
    ACC.z = fmaf(W, V.z, ACC.z); ACC.w = fmaf(W, V.w, ACC.w);

    if (deg <= 64) {
        if (deg > 0) {
            int j = start + lane;
            bool valid = j < end;
            int msrc = valid ? colsrc[j] : 0;
            float e = valid ? es[msrc] + edd : -INFINITY;
            e = fmaxf(e, NEG_SLOPE * e);
            float mx = e;
#pragma unroll
            for (int off = 32; off; off >>= 1) mx = fmaxf(mx, __shfl_xor(mx, off));
            float ee = valid ? expf(e - mx) : 0.f;
            float sum = ee;
#pragma unroll
            for (int off = 32; off; off >>= 1) sum += __shfl_xor(sum, off);
            float w = ee / sum;

            int j2 = 0;
            for (; j2 + 8 <= deg; j2 += 8) {
                int s0 = __shfl(msrc, j2 + 0), s1 = __shfl(msrc, j2 + 1);
                int s2 = __shfl(msrc, j2 + 2), s3 = __shfl(msrc, j2 + 3);
                int s4 = __shfl(msrc, j2 + 4), s5 = __shfl(msrc, j2 + 5);
                int s6 = __shfl(msrc, j2 + 6), s7 = __shfl(msrc, j2 + 7);
                float w0 = __shfl(w, j2 + 0), w1 = __shfl(w, j2 + 1);
                float w2 = __shfl(w, j2 + 2), w3 = __shfl(w, j2 + 3);
                float w4 = __shfl(w, j2 + 4), w5 = __shfl(w, j2 + 5);
                float w6 = __shfl(w, j2 + 6), w7 = __shfl(w, j2 + 7);
                float4 v0 = *(const float4*)(hw + (size_t)s0 * DD + lane * 4);
                float4 v1 = *(const float4*)(hw + (size_t)s1 * DD + lane * 4);
                float4 v2 = *(const float4*)(hw + (size_t)s2 * DD + lane * 4);
                float4 v3 = *(const float4*)(hw + (size_t)s3 * DD + lane * 4);
                float4 v4 = *(const float4*)(hw + (size_t)s4 * DD + lane * 4);
                float4 v5 = *(const float4*)(hw + (size_t)s5 * DD + lane * 4);
                float4 v6 = *(const float4*)(hw + (size_t)s6 * DD + lane * 4);
                float4 v7 = *(const float4*)(hw + (size_t)s7 * DD + lane * 4);
                FMA4(acc0, w0, v0); FMA4(acc1, w1, v1);
                FMA4(acc2, w2, v2); FMA4(acc3, w3, v3);
                FMA4(acc4, w4, v4); FMA4(acc5, w5, v5);
                FMA4(acc6, w6, v6); FMA4(acc7, w7, v7);
            }
            if (j2 + 4 <= deg) {
                int s0 = __shfl(msrc, j2 + 0), s1 = __shfl(msrc, j2 + 1);
                int s2 = __shfl(msrc, j2 + 2), s3 = __shfl(msrc, j2 + 3);
                float w0 = __shfl(w, j2 + 0), w1 = __shfl(w, j2 + 1);
                float w2 = __shfl(w, j2 + 2), w3 = __shfl(w, j2 + 3);
                float4 v0 = *(const float4*)(hw + (size_t)s0 * DD + lane * 4);
                float4 v1 = *(const float4*)(hw + (size_t)s1 * DD + lane * 4);
                float4 v2 = *(const float4*)(hw + (size_t)s2 * DD + lane * 4);
                float4 v3 = *(const float4*)(hw + (size_t)s3 * DD + lane * 4);
                FMA4(acc0, w0, v0); FMA4(acc1, w1, v1);
                FMA4(acc2, w2, v2); FMA4(acc3, w3, v3);
                j2 += 4;
            }
            for (; j2 < deg; ++j2) {
                int   s0 = __shfl(msrc, j2);
                float w0 = __shfl(w, j2);
                float4 v0 = *(const float4*)(hw + (size_t)s0 * DD + lane * 4);
                FMA4(acc0, w0, v0);
            }
        }
    } else {
        float mx = -INFINITY;
        for (int j = start + lane; j < end; j += 64) {
            float e = es[colsrc[j]] + edd;
            e = fmaxf(e, NEG_SLOPE * e);
            mx = fmaxf(mx, e);
        }
#pragma unroll
        for (int off = 32; off; off >>= 1) mx = fmaxf(mx, __shfl_xor(mx, off));
        float sum = 0.f;
        for (int j = start + lane; j < end; j += 64) {
            float e = es[colsrc[j]] + edd;
            e = fmaxf(e, NEG_SLOPE * e);
            float ee = expf(e - mx);
            ealpha[j] = ee;
            sum += ee;
        }
#pragma unroll
        for (int off = 32; off; off >>= 1) sum += __shfl_xor(sum, off);
        float inv = 1.f / sum;
        int j = start;
        for (; j + 4 <= end; j += 4) {
            int s0 = colsrc[j], s1 = colsrc[j + 1], s2 = colsrc[j + 2], s3 = colsrc[j + 3];
            float w0 = ealpha[j] * inv, w1 = ealpha[j + 1] * inv;
            float w2 = ealpha[j + 2] * inv, w3 = ealpha[j + 3] * inv;
            float4 v0 = *(const float4*)(hw + (size_t)s0 * DD + lane * 4);
            float4 v1 = *(const float4*)(hw + (size_t)s1 * DD + lane * 4);
            float4 v2 = *(const float4*)(hw + (size_t)s2 * DD + lane * 4);
            float4 v3 = *(const float4*)(hw + (size_t)s3 * DD + lane * 4);
            FMA4(acc0, w0, v0); FMA4(acc1, w1, v1);
            FMA4(acc2, w2, v2); FMA4(acc3, w3, v3);
        }
        for (; j < end; ++j) {
            int s0 = colsrc[j];
            float w0 = ealpha[j] * inv;
            float4 v0 = *(const float4*)(hw + (size_t)s0 * DD + lane * 4);
            FMA4(acc0, w0, v0);
        }
    }
#undef FMA4

    acc0.x += acc4.x; acc0.y += acc4.y; acc0.z += acc4.z; acc0.w += acc4.w;
    acc1.x += acc5.x; acc1.y += acc5.y; acc1.z += acc5.z; acc1.w += acc5.w;
    acc2.x += acc6.x; acc2.y += acc6.y; acc2.z += acc6.z; acc2.w += acc6.w;
    acc3.x += acc7.x; acc3.y += acc7.y; acc3.z += acc7.z; acc3.w += acc7.w;
    acc0.x += acc1.x; acc0.y += acc1.y; acc0.z += acc1.z; acc0.w += acc1.w;
    acc2.x += acc3.x; acc2.y += acc3.y; acc2.z += acc3.z; acc2.w += acc3.w;
    acc0.x += acc2.x; acc0.y += acc2.y; acc0.z += acc2.z; acc0.w += acc2.w;
    float4 b4 = *(const float4*)(bias + lane * 4);
    acc0.x += b4.x; acc0.y += b4.y; acc0.z += b4.z; acc0.w += b4.w;
    if (RELU) {
        acc0.x = fmaxf(acc0.x, 0.f); acc0.y = fmaxf(acc0.y, 0.f);
        acc0.z = fmaxf(acc0.z, 0.f); acc0.w = fmaxf(acc0.w, 0.f);
    }
    // split-store: 4 hi halves + 4 lo halves (8B each, coalesced)
    size_t base = (size_t)node * DD + lane * 4;
    _Float16 h0 = (_Float16)acc0.x, h1 = (_Float16)acc0.y;
    _Float16 h2 = (_Float16)acc0.z, h3 = (_Float16)acc0.w;
    half4 hv; hv[0] = h0; hv[1] = h1; hv[2] = h2; hv[3] = h3;
    half4 lv;
    lv[0] = (_Float16)(acc0.x - (float)h0); lv[1] = (_Float16)(acc0.y - (float)h1);
    lv[2] = (_Float16)(acc0.z - (float)h2); lv[3] = (_Float16)(acc0.w - (float)h3);
    *(half4*)(hh + base) = hv;
    *(half4*)(hl + base) = lv;
}

// ---------------- driver ----------------

extern "C" void kernel_launch(void* const* d_in, const int* in_sizes, int n_in,
                              void* d_out, int out_size, void* d_ws, size_t ws_size,
                              hipStream_t stream) {
    const float* x     = (const float*)d_in[0];
    const int*   ei    = (const int*)d_in[1];     // [2,E]: src then dst
    const float* W1    = (const float*)d_in[2];
    const float* W2    = (const float*)d_in[3];
    const float* Ws    = (const float*)d_in[4];   // [6,256,256]
    const float* a_src = (const float*)d_in[5];
    const float* a_dst = (const float*)d_in[6];
    const float* bias  = (const float*)d_in[7];
    const float* W3    = (const float*)d_in[8];   // [512,256]
    float* out = (float*)d_out;

    const int* src = ei;
    const int* dst = ei + EEDGES;

    const size_t ND = (size_t)NNODES * DD;

    // workspace carve-up
    float* bufA   = (float*)d_ws;            // ND fp32 (hw)
    float* es     = bufA + ND;               // N
    float* edv    = es + NNODES;             // N
    float* ealpha = edv + NNODES;            // E
    int*   rowptr = (int*)(ealpha + EEDGES); // N+1
    int*   cursor = rowptr + (NNODES + 1);   // N
    int*   colsrc = cursor + NNODES;         // E
    int*   bsums  = colsrc + EEDGES;         // SCAN_BLOCKS
    _Float16* P0h = (_Float16*)(((uintptr_t)(bsums + SCAN_BLOCKS) + 15) & ~(uintptr_t)15);
    _Float16* P0l = P0h + ND;
    _Float16* P1h = P0l + ND;
    _Float16* P1l = P1h + ND;
    _Float16* WT  = P1l + ND;                // 9 weight pairs (transposed split)
    const size_t WSZ = (size_t)DD * DD;      // 65536

    // --- CSR build ---
    zero_ints_k<<<(NNODES + 1 + 255) / 256, 256, 0, stream>>>(rowptr, NNODES + 1);
    hist_k<<<(EEDGES + 255) / 256, 256, 0, stream>>>(dst, rowptr);
    scan1_k<<<SCAN_BLOCKS, 256, 0, stream>>>(rowptr, bsums);
    scan2_k<<<1, 128, 0, stream>>>(bsums);
    scan3_k<<<SCAN_BLOCKS, 256, 0, stream>>>(rowptr, bsums, cursor);
    scatter_k<<<(EEDGES + 255) / 256, 256, 0, stream>>>(src, dst, cursor, colsrc);

    // --- weight conversion (transpose + fp16 split) ---
    const int WBLK = (DD * DD + 255) / 256;
    cvt_w_k<false><<<WBLK, 256, 0, stream>>>(W1, WT + 0 * 2 * WSZ, WT + 0 * 2 * WSZ + WSZ);
    cvt_w_k<false><<<WBLK, 256, 0, stream>>>(W2, WT + 1 * 2 * WSZ, WT + 1 * 2 * WSZ + WSZ);
    for (int l = 0; l < 6; ++l)
        cvt_w_k<false><<<WBLK, 256, 0, stream>>>(Ws + (size_t)l * WSZ,
                                                 WT + (2 + l) * 2 * WSZ,
                                                 WT + (2 + l) * 2 * WSZ + WSZ);
    cvt_w_k<true><<<WBLK, 256, 0, stream>>>(W3, WT + 8 * 2 * WSZ, WT + 8 * 2 * WSZ + WSZ);

    // --- x split ---
    cvt_split_k<<<(int)((ND + 255) / 256), 256, 0, stream>>>(x, P0h, P0l, (int)ND);

    dim3 g16(DD / 64, (NNODES + 63) / 64);   // (4, 313)
    const int nodeBlocks = (NNODES + 3) / 4;

#define WTH(i) (WT + (i) * 2 * WSZ)
#define WTL(i) (WT + (i) * 2 * WSZ + WSZ)

    // t = x@W1 (split out), h0 = t@W2 (split out)
    gemm16_k<true><<<g16, 256, 0, stream>>>(P0h, P0l, WTH(0), WTL(0), nullptr, P1h, P1l, NNODES);
    gemm16_k<true><<<g16, 256, 0, stream>>>(P1h, P1l, WTH(1), WTL(1), nullptr, P0h, P0l, NNODES);

    // 6 GAT layers: h (P0 split) -> hw (bufA fp32) -> agg -> h (P0 split)
    for (int l = 0; l < 6; ++l) {
        gemm16_k<false><<<g16, 256, 0, stream>>>(P0h, P0l, WTH(2 + l), WTL(2 + l),
                                                 bufA, nullptr, nullptr, NNODES);
        dots_k<<<nodeBlocks, 256, 0, stream>>>(bufA, a_src + (size_t)l * DD,
                                               a_dst + (size_t)l * DD, es, edv);
        if (l < 5)
            gat_agg_k<false><<<nodeBlocks, 256, 0, stream>>>(bufA, es, edv, rowptr, colsrc,
                                                             ealpha, bias + (size_t)l * DD,
                                                             P0h, P0l);
        else
            gat_agg_k<true><<<nodeBlocks, 256, 0, stream>>>(bufA, es, edv, rowptr, colsrc,
                                                            ealpha, bias + (size_t)l * DD,
                                                            P0h, P0l);
    }

    // out = relu(h) @ (W3_top + W3_bot)  (relu already applied in layer-5 agg)
    gemm16_k<false><<<g16, 256, 0, stream>>>(P0h, P0l, WTH(8), WTL(8), out,
                                             nullptr, nullptr, NNODES);
#undef WTH
#undef WTL
}